// Round 1
// baseline (726.213 us; speedup 1.0000x reference)
//
#include <hip/hip_runtime.h>

// Problem constants
#define CCH   256
#define NHEAD 8
#define HDIM  32
#define NTOK  512      // tokens per window (8*8*8)
#define NWIN  64       // windows (4*4*4)
#define QSCALE 0.17677669529663687f  // 32^-0.5

// workspace layout (floats)
#define QOFF 0u
#define KOFF 8388608u
#define VOFF 16777216u
#define YOFF 25165824u

// token (w*512+n) -> flat spatial offset (*CCH) in x/out with +4 cyclic shift
__device__ __forceinline__ int spatial_off(int token) {
    int w = token >> 9, n = token & 511;
    int wh = w >> 4, ww = (w >> 2) & 3, wd = w & 3;
    int h1 = n >> 6, w1 = (n >> 3) & 7, d1 = n & 7;
    int gh = (wh * 8 + h1 + 4) & 31;
    int gw = (ww * 8 + w1 + 4) & 31;
    int gd = (wd * 8 + d1 + 4) & 31;
    return ((gh * 32 + gw) * 32 + gd) * CCH;
}

__device__ __forceinline__ int region_cnt(int wh, int ww, int wd, int h1, int w1, int d1) {
    int rh = (wh < 3) ? 0 : (h1 < 4 ? 1 : 2);
    int rw = (ww < 3) ? 0 : (w1 < 4 ? 1 : 2);
    int rd = (wd < 3) ? 0 : (d1 < 4 ? 1 : 2);
    return rh * 9 + rw * 3 + rd;
}

// ---------------- QKV projection: [32768,256] @ W^T[256,768] + b ----------------
__global__ __launch_bounds__(256) void qkv_kernel(
    const float* __restrict__ x, const float* __restrict__ Wq,
    const float* __restrict__ bq,
    float* __restrict__ Q, float* __restrict__ K, float* __restrict__ V) {
    __shared__ float As[16][68];
    __shared__ float Bs[16][68];
    const int t = threadIdx.x;
    const int mtile = blockIdx.y, ntile = blockIdx.x;
    const int lr = t >> 2, lq = t & 3;
    const int ty = t >> 4, tx = t & 15;

    const float* abase = x + spatial_off(mtile * 64 + lr);
    const float* bbase = Wq + (ntile * 64 + lr) * CCH;

    float acc[4][4] = {};
    for (int k0 = 0; k0 < 256; k0 += 16) {
        float4 av = *(const float4*)(abase + k0 + lq * 4);
        float4 bv = *(const float4*)(bbase + k0 + lq * 4);
        __syncthreads();
        As[lq*4+0][lr] = av.x; As[lq*4+1][lr] = av.y; As[lq*4+2][lr] = av.z; As[lq*4+3][lr] = av.w;
        Bs[lq*4+0][lr] = bv.x; Bs[lq*4+1][lr] = bv.y; Bs[lq*4+2][lr] = bv.z; Bs[lq*4+3][lr] = bv.w;
        __syncthreads();
#pragma unroll
        for (int kk = 0; kk < 16; ++kk) {
            float a0 = As[kk][ty*4+0], a1 = As[kk][ty*4+1], a2 = As[kk][ty*4+2], a3 = As[kk][ty*4+3];
            float b0 = Bs[kk][tx*4+0], b1 = Bs[kk][tx*4+1], b2 = Bs[kk][tx*4+2], b3 = Bs[kk][tx*4+3];
            acc[0][0] += a0*b0; acc[0][1] += a0*b1; acc[0][2] += a0*b2; acc[0][3] += a0*b3;
            acc[1][0] += a1*b0; acc[1][1] += a1*b1; acc[1][2] += a1*b2; acc[1][3] += a1*b3;
            acc[2][0] += a2*b0; acc[2][1] += a2*b1; acc[2][2] += a2*b2; acc[2][3] += a2*b3;
            acc[3][0] += a3*b0; acc[3][1] += a3*b1; acc[3][2] += a3*b2; acc[3][3] += a3*b3;
        }
    }
    const int jbase = ntile * 64 + tx * 4;
    const int three = jbase >> 8, head = (jbase >> 5) & 7, hd = jbase & 31;
    float* dst = (three == 0) ? Q : ((three == 1) ? K : V);
    const float sc = (three == 0) ? QSCALE : 1.0f;
    const float b0 = bq[jbase+0], b1 = bq[jbase+1], b2 = bq[jbase+2], b3 = bq[jbase+3];
#pragma unroll
    for (int i = 0; i < 4; ++i) {
        int token = mtile * 64 + ty * 4 + i;
        int w = token >> 9, n = token & 511;
        float4 v;
        v.x = (acc[i][0] + b0) * sc;
        v.y = (acc[i][1] + b1) * sc;
        v.z = (acc[i][2] + b2) * sc;
        v.w = (acc[i][3] + b3) * sc;
        *(float4*)(dst + ((size_t)(w * NHEAD + head) * NTOK + n) * HDIM + hd) = v;
    }
}

// ---------------- windowed attention: per (window, head, 16-query tile) ----------------
__global__ __launch_bounds__(256) void attn_kernel(
    const float* __restrict__ Q, const float* __restrict__ K,
    const float* __restrict__ V, const float* __restrict__ rpb,
    float* __restrict__ Y) {
    __shared__ float Qs[16][36];
    __shared__ float KV[64][36];
    __shared__ float Ss[16][516];
    __shared__ float red[16][16];
    __shared__ float rowL[16];

    const int t = threadIdx.x;
    const int bid = blockIdx.x;
    const int w = bid >> 8;
    const int head = (bid >> 5) & 7;
    const int qt = bid & 31;
    const int wh = w >> 4, ww = (w >> 2) & 3, wd = w & 3;

    const float* Qb = Q + ((size_t)(w * NHEAD + head) * NTOK + qt * 16) * HDIM;
    const float* Kb = K + (size_t)(w * NHEAD + head) * NTOK * HDIM;
    const float* Vb = V + (size_t)(w * NHEAD + head) * NTOK * HDIM;

    if (t < 128) {
        int r = t >> 3, q = t & 7;
        *(float4*)&Qs[r][q * 4] = *(const float4*)(Qb + r * 32 + q * 4);
    }
    __syncthreads();

    const int qig = t & 7, tk = t >> 3;
    float q0[32], q1[32];
#pragma unroll
    for (int d = 0; d < 32; ++d) { q0[d] = Qs[qig][d]; q1[d] = Qs[qig + 8][d]; }

    const int nq0 = qt * 16 + qig, nq1 = nq0 + 8;
    const int h1q0 = nq0 >> 6, w1q0 = (nq0 >> 3) & 7, d1q0 = nq0 & 7;
    const int h1q1 = nq1 >> 6, w1q1 = (nq1 >> 3) & 7, d1q1 = nq1 & 7;
    const int cq0 = region_cnt(wh, ww, wd, h1q0, w1q0, d1q0);
    const int cq1 = region_cnt(wh, ww, wd, h1q1, w1q1, d1q1);

    const int lr = t >> 2, lq = t & 3;

    // ---- phase 1: S = q@k^T + bias + mask ----
    for (int tile = 0; tile < 8; ++tile) {
        const float* kr = Kb + (tile * 64 + lr) * 32 + lq * 4;
        float4 kv0 = *(const float4*)(kr);
        float4 kv1 = *(const float4*)(kr + 16);
        __syncthreads();
        *(float4*)&KV[lr][lq * 4] = kv0;
        *(float4*)&KV[lr][lq * 4 + 16] = kv1;
        __syncthreads();
#pragma unroll
        for (int kk = 0; kk < 2; ++kk) {
            int kjl = tk + kk * 32;
            int kj = tile * 64 + kjl;
            float acc0 = 0.f, acc1 = 0.f;
#pragma unroll
            for (int d = 0; d < 32; ++d) {
                float kvv = KV[kjl][d];
                acc0 += q0[d] * kvv;
                acc1 += q1[d] * kvv;
            }
            int h1k = kj >> 6, w1k = (kj >> 3) & 7, d1k = kj & 7;
            int ck = region_cnt(wh, ww, wd, h1k, w1k, d1k);
            int i0 = ((h1q0 - h1k + 7) * 15 + (w1q0 - w1k + 7)) * 15 + (d1q0 - d1k + 7);
            int i1 = ((h1q1 - h1k + 7) * 15 + (w1q1 - w1k + 7)) * 15 + (d1q1 - d1k + 7);
            float s0 = acc0 + rpb[i0 * 8 + head] + ((cq0 == ck) ? 0.f : -100.f);
            float s1 = acc1 + rpb[i1 * 8 + head] + ((cq1 == ck) ? 0.f : -100.f);
            Ss[qig][kj] = s0;
            Ss[qig + 8][kj] = s1;
        }
    }
    __syncthreads();

    // ---- softmax over rows of Ss (16 rows x 512) ----
    {
        const int g = t >> 4, l = t & 15;
        float pm = -1e30f;
        for (int i = 0; i < 32; ++i) pm = fmaxf(pm, Ss[g][l + i * 16]);
        red[g][l] = pm;
        __syncthreads();
        float m;
        if (l == 0) {
            m = red[g][0];
            for (int i = 1; i < 16; ++i) m = fmaxf(m, red[g][i]);
            red[g][0] = m;
        }
        __syncthreads();
        m = red[g][0];
        float ps = 0.f;
        for (int i = 0; i < 32; ++i) {
            float e = __expf(Ss[g][l + i * 16] - m);
            Ss[g][l + i * 16] = e;
            ps += e;
        }
        __syncthreads();   // all Ss writes done before red reuse? red[g][0] still needed -- no, m consumed
        red[g][l] = ps;
        __syncthreads();
        if (l == 0) {
            float s = 0.f;
            for (int i = 0; i < 16; ++i) s += red[g][i];
            rowL[g] = s;
        }
    }

    // ---- phase 2: O = P @ V (partial over kj-slot, then reduce) ----
    const int qg = t & 3, hdg = (t >> 2) & 7, ks = t >> 5;
    float acc[4][4] = {};
    for (int tile = 0; tile < 8; ++tile) {
        const float* vr = Vb + (tile * 64 + lr) * 32 + lq * 4;
        float4 v0 = *(const float4*)(vr);
        float4 v1 = *(const float4*)(vr + 16);
        __syncthreads();
        *(float4*)&KV[lr][lq * 4] = v0;
        *(float4*)&KV[lr][lq * 4 + 16] = v1;
        __syncthreads();
#pragma unroll
        for (int mI = 0; mI < 8; ++mI) {
            int kjl = ks + mI * 8;
            int kj = tile * 64 + kjl;
            float p0 = Ss[qg * 4 + 0][kj];
            float p1 = Ss[qg * 4 + 1][kj];
            float p2 = Ss[qg * 4 + 2][kj];
            float p3 = Ss[qg * 4 + 3][kj];
            float4 vv = *(const float4*)&KV[kjl][hdg * 4];
            acc[0][0] += p0 * vv.x; acc[0][1] += p0 * vv.y; acc[0][2] += p0 * vv.z; acc[0][3] += p0 * vv.w;
            acc[1][0] += p1 * vv.x; acc[1][1] += p1 * vv.y; acc[1][2] += p1 * vv.z; acc[1][3] += p1 * vv.w;
            acc[2][0] += p2 * vv.x; acc[2][1] += p2 * vv.y; acc[2][2] += p2 * vv.z; acc[2][3] += p2 * vv.w;
            acc[3][0] += p3 * vv.x; acc[3][1] += p3 * vv.y; acc[3][2] += p3 * vv.z; acc[3][3] += p3 * vv.w;
        }
    }
    __syncthreads();
    float* Sf = &Ss[0][0];
#pragma unroll
    for (int i = 0; i < 4; ++i)
#pragma unroll
        for (int j = 0; j < 4; ++j)
            Sf[ks * 512 + (qg * 4 + i) * 32 + hdg * 4 + j] = acc[i][j];
    __syncthreads();
    for (int o = t; o < 512; o += 256) {
        float s = 0.f;
#pragma unroll
        for (int k = 0; k < 8; ++k) s += Sf[k * 512 + o];
        int qi = o >> 5, hd = o & 31;
        float val = s / rowL[qi];
        Y[((size_t)(w * NTOK) + qt * 16 + qi) * CCH + head * HDIM + hd] = val;
    }
}

// ---------------- proj: Y[32768,256] @ Wp^T + b, scatter w/ reverse shift ----------------
__global__ __launch_bounds__(256) void proj_kernel(
    const float* __restrict__ Y, const float* __restrict__ Wp,
    const float* __restrict__ bp, float* __restrict__ out) {
    __shared__ float As[16][68];
    __shared__ float Bs[16][68];
    const int t = threadIdx.x;
    const int mtile = blockIdx.y, ntile = blockIdx.x;
    const int lr = t >> 2, lq = t & 3;
    const int ty = t >> 4, tx = t & 15;

    const float* abase = Y + (size_t)(mtile * 64 + lr) * CCH;
    const float* bbase = Wp + (ntile * 64 + lr) * CCH;

    float acc[4][4] = {};
    for (int k0 = 0; k0 < 256; k0 += 16) {
        float4 av = *(const float4*)(abase + k0 + lq * 4);
        float4 bv = *(const float4*)(bbase + k0 + lq * 4);
        __syncthreads();
        As[lq*4+0][lr] = av.x; As[lq*4+1][lr] = av.y; As[lq*4+2][lr] = av.z; As[lq*4+3][lr] = av.w;
        Bs[lq*4+0][lr] = bv.x; Bs[lq*4+1][lr] = bv.y; Bs[lq*4+2][lr] = bv.z; Bs[lq*4+3][lr] = bv.w;
        __syncthreads();
#pragma unroll
        for (int kk = 0; kk < 16; ++kk) {
            float a0 = As[kk][ty*4+0], a1 = As[kk][ty*4+1], a2 = As[kk][ty*4+2], a3 = As[kk][ty*4+3];
            float b0 = Bs[kk][tx*4+0], b1 = Bs[kk][tx*4+1], b2 = Bs[kk][tx*4+2], b3 = Bs[kk][tx*4+3];
            acc[0][0] += a0*b0; acc[0][1] += a0*b1; acc[0][2] += a0*b2; acc[0][3] += a0*b3;
            acc[1][0] += a1*b0; acc[1][1] += a1*b1; acc[1][2] += a1*b2; acc[1][3] += a1*b3;
            acc[2][0] += a2*b0; acc[2][1] += a2*b1; acc[2][2] += a2*b2; acc[2][3] += a2*b3;
            acc[3][0] += a3*b0; acc[3][1] += a3*b1; acc[3][2] += a3*b2; acc[3][3] += a3*b3;
        }
    }
    const int jbase = ntile * 64 + tx * 4;
    const float b0 = bp[jbase+0], b1 = bp[jbase+1], b2 = bp[jbase+2], b3 = bp[jbase+3];
#pragma unroll
    for (int i = 0; i < 4; ++i) {
        int token = mtile * 64 + ty * 4 + i;
        float4 v;
        v.x = acc[i][0] + b0;
        v.y = acc[i][1] + b1;
        v.z = acc[i][2] + b2;
        v.w = acc[i][3] + b3;
        *(float4*)(out + spatial_off(token) + jbase) = v;
    }
}

extern "C" void kernel_launch(void* const* d_in, const int* in_sizes, int n_in,
                              void* d_out, int out_size, void* d_ws, size_t ws_size,
                              hipStream_t stream) {
    const float* x      = (const float*)d_in[0];
    const float* qkv_w  = (const float*)d_in[1];
    const float* qkv_b  = (const float*)d_in[2];
    const float* proj_w = (const float*)d_in[3];
    const float* proj_b = (const float*)d_in[4];
    const float* rpb    = (const float*)d_in[5];
    float* out = (float*)d_out;
    float* ws  = (float*)d_ws;

    float* Q = ws + QOFF;
    float* K = ws + KOFF;
    float* V = ws + VOFF;
    float* Y = ws + YOFF;

    qkv_kernel<<<dim3(12, 512), dim3(256), 0, stream>>>(x, qkv_w, qkv_b, Q, K, V);
    attn_kernel<<<dim3(16384), dim3(256), 0, stream>>>(Q, K, V, rpb, Y);
    proj_kernel<<<dim3(4, 512), dim3(256), 0, stream>>>(Y, proj_w, proj_b, out);
}

// Round 2
// 455.392 us; speedup vs baseline: 1.5947x; 1.5947x over previous
//
#include <hip/hip_runtime.h>

typedef __attribute__((ext_vector_type(8))) short short8;
typedef __attribute__((ext_vector_type(4))) float floatx4;

#define CCH   256
#define QSCALE 0.17677669529663687f  // 32^-0.5

__device__ __forceinline__ unsigned short f2bf(float f) {
    unsigned u = __float_as_uint(f);
    u = u + 0x7fffu + ((u >> 16) & 1u);
    return (unsigned short)(u >> 16);
}
__device__ __forceinline__ float bf2f(unsigned short h) {
    return __uint_as_float(((unsigned)h) << 16);
}

// token (w*512+n) -> flat spatial offset (*CCH) in x/out with +4 cyclic shift
__device__ __forceinline__ int spatial_off(int token) {
    int w = token >> 9, n = token & 511;
    int wh = w >> 4, ww = (w >> 2) & 3, wd = w & 3;
    int h1 = n >> 6, w1 = (n >> 3) & 7, d1 = n & 7;
    int gh = (wh * 8 + h1 + 4) & 31;
    int gw = (ww * 8 + w1 + 4) & 31;
    int gd = (wd * 8 + d1 + 4) & 31;
    return ((gh * 32 + gw) * 32 + gd) * CCH;
}

// ---------------- QKV projection (fp32 VALU GEMM), bf16 epilogue ----------------
__global__ __launch_bounds__(256) void qkv_kernel(
    const float* __restrict__ x, const float* __restrict__ Wq,
    const float* __restrict__ bq,
    ushort* __restrict__ Q, ushort* __restrict__ K, ushort* __restrict__ V) {
    __shared__ float As[16][68];
    __shared__ float Bs[16][68];
    const int t = threadIdx.x;
    const int mtile = blockIdx.y, ntile = blockIdx.x;
    const int lr = t >> 2, lq = t & 3;
    const int ty = t >> 4, tx = t & 15;

    const float* abase = x + spatial_off(mtile * 64 + lr);
    const float* bbase = Wq + (ntile * 64 + lr) * CCH;

    float acc[4][4] = {};
    for (int k0 = 0; k0 < 256; k0 += 16) {
        float4 av = *(const float4*)(abase + k0 + lq * 4);
        float4 bv = *(const float4*)(bbase + k0 + lq * 4);
        __syncthreads();
        As[lq*4+0][lr] = av.x; As[lq*4+1][lr] = av.y; As[lq*4+2][lr] = av.z; As[lq*4+3][lr] = av.w;
        Bs[lq*4+0][lr] = bv.x; Bs[lq*4+1][lr] = bv.y; Bs[lq*4+2][lr] = bv.z; Bs[lq*4+3][lr] = bv.w;
        __syncthreads();
#pragma unroll
        for (int kk = 0; kk < 16; ++kk) {
            float a0 = As[kk][ty*4+0], a1 = As[kk][ty*4+1], a2 = As[kk][ty*4+2], a3 = As[kk][ty*4+3];
            float b0 = Bs[kk][tx*4+0], b1 = Bs[kk][tx*4+1], b2 = Bs[kk][tx*4+2], b3 = Bs[kk][tx*4+3];
            acc[0][0] += a0*b0; acc[0][1] += a0*b1; acc[0][2] += a0*b2; acc[0][3] += a0*b3;
            acc[1][0] += a1*b0; acc[1][1] += a1*b1; acc[1][2] += a1*b2; acc[1][3] += a1*b3;
            acc[2][0] += a2*b0; acc[2][1] += a2*b1; acc[2][2] += a2*b2; acc[2][3] += a2*b3;
            acc[3][0] += a3*b0; acc[3][1] += a3*b1; acc[3][2] += a3*b2; acc[3][3] += a3*b3;
        }
    }
    const int jbase = ntile * 64 + tx * 4;
    const int three = jbase >> 8, head = (jbase >> 5) & 7, hd = jbase & 31;
    ushort* dst = (three == 0) ? Q : ((three == 1) ? K : V);
    const float sc = (three == 0) ? QSCALE : 1.0f;
    const float b0 = bq[jbase+0], b1 = bq[jbase+1], b2 = bq[jbase+2], b3 = bq[jbase+3];
#pragma unroll
    for (int i = 0; i < 4; ++i) {
        int token = mtile * 64 + ty * 4 + i;
        int w = token >> 9, n = token & 511;
        ushort4 s;
        s.x = f2bf((acc[i][0] + b0) * sc);
        s.y = f2bf((acc[i][1] + b1) * sc);
        s.z = f2bf((acc[i][2] + b2) * sc);
        s.w = f2bf((acc[i][3] + b3) * sc);
        *(ushort4*)(dst + ((size_t)(w * 8 + head) * 512 + n) * 32 + hd) = s;
    }
}

// ---------------- rel-pos bias, pre-permuted into MFMA C-fragment order ----------------
// BF[head][qt 0..31][kt 0..31][lane 0..63][reg 0..3] bf16
__global__ __launch_bounds__(256) void bias_prep(const float* __restrict__ rpb,
                                                 ushort* __restrict__ BF) {
    int tid = blockIdx.x * 256 + threadIdx.x;   // 524288 total
    int lane = tid & 63, kt = (tid >> 6) & 31, qt = (tid >> 11) & 31, head = tid >> 16;
    int quad = lane >> 4, colc = lane & 15;
    int key = kt * 16 + colc;
    int h1k = key >> 6, w1k = (key >> 3) & 7, d1k = key & 7;
    ushort4 out;
#pragma unroll
    for (int r = 0; r < 4; ++r) {
        int qrow = qt * 16 + quad * 4 + r;
        int dh = (qrow >> 6) - h1k + 7;
        int dw = ((qrow >> 3) & 7) - w1k + 7;
        int dd = (qrow & 7) - d1k + 7;
        int idx = (dh * 15 + dw) * 15 + dd;
        ((ushort*)&out)[r] = f2bf(rpb[idx * 8 + head]);
    }
    *(ushort4*)(BF + (size_t)tid * 4) = out;
}

// ---------------- MFMA windowed attention ----------------
// block = (window, head, 64-row q-strip); 4 waves, wave owns 16 q rows
__global__ __launch_bounds__(256, 2) void attn_kernel(
    const ushort* __restrict__ Q, const ushort* __restrict__ K,
    const ushort* __restrict__ V, const ushort* __restrict__ BF,
    float* __restrict__ Y) {
    __shared__ short Kl[512 * 32];       // row-major [key][hd] bf16
    __shared__ short Vs[512 * 32];       // B-fragment order [kt*2+nt][lane][j]
    __shared__ short Ps[4][16 * 40];     // per-wave P transpose buffer (stride 40)

    const int t = threadIdx.x;
    const int bid = blockIdx.x;
    const int w = bid >> 6, head = (bid >> 3) & 7, qs = bid & 7;
    const int wh = w >> 4, ww = (w >> 2) & 3, wd = w & 3;
    const int wv = t >> 6, lane = t & 63, quad = lane >> 4, col = lane & 15;
    const int qt = qs * 4 + wv;

    const ushort* Kg = K + (size_t)(w * 8 + head) * 512 * 32;
    const ushort* Vg = V + (size_t)(w * 8 + head) * 512 * 32;

    // ---- stage K (contiguous copy) and V (fragment-scatter) ----
#pragma unroll
    for (int i = 0; i < 8; ++i) {
        int e = (i * 256 + t) * 8;
        *(short8*)(Kl + e) = *(const short8*)(Kg + e);
        short8 v = *(const short8*)(Vg + e);
        int r = e >> 5, c0 = e & 31;
        int base = (((r >> 5) * 2 + (c0 >> 4)) * 64 + ((r >> 3) & 3) * 16 + (c0 & 15)) * 8 + (r & 7);
#pragma unroll
        for (int m = 0; m < 8; ++m) Vs[base + m * 8] = v[m];
    }

    // Q fragment (A-layout): lane reads 8 contiguous bf16 of its q-row
    short8 qf = *(const short8*)(Q + ((size_t)(w * 8 + head) * 512 + qt * 16 + col) * 32 + quad * 8);
    __syncthreads();

    floatx4 zf = {0.f, 0.f, 0.f, 0.f};
    floatx4 acc[32];
    // ---- S = Q K^T : 32 column-tiles, K-frag reads are contiguous 1KB sweeps ----
#pragma unroll
    for (int tt = 0; tt < 32; ++tt) {
        short8 kf = *(const short8*)(Kl + tt * 512 + col * 32 + quad * 8);
        acc[tt] = __builtin_amdgcn_mfma_f32_16x16x32_bf16(qf, kf, zf, 0, 0, 0);
    }

    // ---- bias + shift mask ----
    const ushort* bfp = BF + ((size_t)(head * 32 + qt) * 32 * 64 + lane) * 4;
    const bool boundary = (wh == 3) | (ww == 3) | (wd == 3);
    int cq[4];
#pragma unroll
    for (int r = 0; r < 4; ++r) {
        int qrow = qt * 16 + quad * 4 + r;
        int ch = (wh == 3) ? (1 + ((qrow >> 8) & 1)) : 0;
        int cw = (ww == 3) ? (1 + ((qrow >> 5) & 1)) : 0;
        int cd = (wd == 3) ? (1 + ((qrow >> 2) & 1)) : 0;
        cq[r] = ch * 16 + cw * 4 + cd;
    }
#pragma unroll
    for (int tt = 0; tt < 32; ++tt) {
        ushort4 bv = *(const ushort4*)(bfp + tt * 256);
        acc[tt][0] += bf2f(bv.x);
        acc[tt][1] += bf2f(bv.y);
        acc[tt][2] += bf2f(bv.z);
        acc[tt][3] += bf2f(bv.w);
        if (boundary) {
            int key = tt * 16 + col;
            int ch = (wh == 3) ? (1 + ((key >> 8) & 1)) : 0;
            int cw = (ww == 3) ? (1 + ((key >> 5) & 1)) : 0;
            int cd = (wd == 3) ? (1 + ((key >> 2) & 1)) : 0;
            int ck = ch * 16 + cw * 4 + cd;
#pragma unroll
            for (int r = 0; r < 4; ++r)
                acc[tt][r] += (cq[r] == ck) ? 0.f : -100.f;
        }
    }

    // ---- register-resident softmax (rows live in 16 col-lanes) ----
    float rm[4], rs[4];
#pragma unroll
    for (int r = 0; r < 4; ++r) {
        float m = acc[0][r];
#pragma unroll
        for (int tt = 1; tt < 32; ++tt) m = fmaxf(m, acc[tt][r]);
        m = fmaxf(m, __shfl_xor(m, 1));
        m = fmaxf(m, __shfl_xor(m, 2));
        m = fmaxf(m, __shfl_xor(m, 4));
        m = fmaxf(m, __shfl_xor(m, 8));
        rm[r] = m * 1.442695041f;
        rs[r] = 0.f;
    }
#pragma unroll
    for (int tt = 0; tt < 32; ++tt) {
#pragma unroll
        for (int r = 0; r < 4; ++r) {
            float e = exp2f(fmaf(acc[tt][r], 1.442695041f, -rm[r]));
            acc[tt][r] = e;
            rs[r] += e;
        }
    }
#pragma unroll
    for (int r = 0; r < 4; ++r) {
        rs[r] += __shfl_xor(rs[r], 1);
        rs[r] += __shfl_xor(rs[r], 2);
        rs[r] += __shfl_xor(rs[r], 4);
        rs[r] += __shfl_xor(rs[r], 8);
    }

    // ---- O = P V : C-layout -> A-layout via per-wave LDS round-trip ----
    short* PsW = &Ps[wv][0];
    floatx4 o0 = zf, o1 = zf;
#pragma unroll
    for (int kt = 0; kt < 16; ++kt) {
#pragma unroll
        for (int ttt = 0; ttt < 2; ++ttt) {
            floatx4 p = acc[kt * 2 + ttt];
#pragma unroll
            for (int r = 0; r < 4; ++r)
                PsW[(quad * 4 + r) * 40 + ttt * 16 + col] = (short)f2bf(p[r]);
        }
        asm volatile("s_waitcnt lgkmcnt(0)" ::: "memory");
        short8 pa = *(const short8*)(PsW + col * 40 + quad * 8);
        short8 v0 = *(const short8*)(Vs + (kt * 2 + 0) * 512 + lane * 8);
        short8 v1 = *(const short8*)(Vs + (kt * 2 + 1) * 512 + lane * 8);
        o0 = __builtin_amdgcn_mfma_f32_16x16x32_bf16(pa, v0, o0, 0, 0, 0);
        o1 = __builtin_amdgcn_mfma_f32_16x16x32_bf16(pa, v1, o1, 0, 0, 0);
        asm volatile("" ::: "memory");   // keep next iter's Ps writes below this iter's reads
    }

    // ---- epilogue: normalize, write Y[token][C] fp32 ----
    float* Yb = Y + ((size_t)(w * 512) + qt * 16) * 256 + head * 32;
#pragma unroll
    for (int r = 0; r < 4; ++r) {
        float inv = 1.0f / rs[r];
        int row = quad * 4 + r;
        Yb[row * 256 + col] = o0[r] * inv;
        Yb[row * 256 + 16 + col] = o1[r] * inv;
    }
}

// ---------------- proj: Y[32768,256] @ Wp^T + b, scatter w/ reverse shift ----------------
__global__ __launch_bounds__(256) void proj_kernel(
    const float* __restrict__ Y, const float* __restrict__ Wp,
    const float* __restrict__ bp, float* __restrict__ out) {
    __shared__ float As[16][68];
    __shared__ float Bs[16][68];
    const int t = threadIdx.x;
    const int mtile = blockIdx.y, ntile = blockIdx.x;
    const int lr = t >> 2, lq = t & 3;
    const int ty = t >> 4, tx = t & 15;

    const float* abase = Y + (size_t)(mtile * 64 + lr) * CCH;
    const float* bbase = Wp + (ntile * 64 + lr) * CCH;

    float acc[4][4] = {};
    for (int k0 = 0; k0 < 256; k0 += 16) {
        float4 av = *(const float4*)(abase + k0 + lq * 4);
        float4 bv = *(const float4*)(bbase + k0 + lq * 4);
        __syncthreads();
        As[lq*4+0][lr] = av.x; As[lq*4+1][lr] = av.y; As[lq*4+2][lr] = av.z; As[lq*4+3][lr] = av.w;
        Bs[lq*4+0][lr] = bv.x; Bs[lq*4+1][lr] = bv.y; Bs[lq*4+2][lr] = bv.z; Bs[lq*4+3][lr] = bv.w;
        __syncthreads();
#pragma unroll
        for (int kk = 0; kk < 16; ++kk) {
            float a0 = As[kk][ty*4+0], a1 = As[kk][ty*4+1], a2 = As[kk][ty*4+2], a3 = As[kk][ty*4+3];
            float b0 = Bs[kk][tx*4+0], b1 = Bs[kk][tx*4+1], b2 = Bs[kk][tx*4+2], b3 = Bs[kk][tx*4+3];
            acc[0][0] += a0*b0; acc[0][1] += a0*b1; acc[0][2] += a0*b2; acc[0][3] += a0*b3;
            acc[1][0] += a1*b0; acc[1][1] += a1*b1; acc[1][2] += a1*b2; acc[1][3] += a1*b3;
            acc[2][0] += a2*b0; acc[2][1] += a2*b1; acc[2][2] += a2*b2; acc[2][3] += a2*b3;
            acc[3][0] += a3*b0; acc[3][1] += a3*b1; acc[3][2] += a3*b2; acc[3][3] += a3*b3;
        }
    }
    const int jbase = ntile * 64 + tx * 4;
    const float b0 = bp[jbase+0], b1 = bp[jbase+1], b2 = bp[jbase+2], b3 = bp[jbase+3];
#pragma unroll
    for (int i = 0; i < 4; ++i) {
        int token = mtile * 64 + ty * 4 + i;
        float4 v;
        v.x = acc[i][0] + b0;
        v.y = acc[i][1] + b1;
        v.z = acc[i][2] + b2;
        v.w = acc[i][3] + b3;
        *(float4*)(out + spatial_off(token) + jbase) = v;
    }
}

extern "C" void kernel_launch(void* const* d_in, const int* in_sizes, int n_in,
                              void* d_out, int out_size, void* d_ws, size_t ws_size,
                              hipStream_t stream) {
    const float* x      = (const float*)d_in[0];
    const float* qkv_w  = (const float*)d_in[1];
    const float* qkv_b  = (const float*)d_in[2];
    const float* proj_w = (const float*)d_in[3];
    const float* proj_b = (const float*)d_in[4];
    const float* rpb    = (const float*)d_in[5];
    float* out = (float*)d_out;

    // ws layout: Q,K,V bf16 (16.78 MB each), Y fp32 (33.5 MB), bias-frag bf16 (4.2 MB) = 88 MB
    ushort* Q  = (ushort*)d_ws;
    ushort* K  = Q + 8388608;
    ushort* V  = K + 8388608;
    float*  Y  = (float*)(V + 8388608);
    ushort* BF = (ushort*)(Y + 8388608);

    bias_prep<<<dim3(2048), dim3(256), 0, stream>>>(rpb, BF);
    qkv_kernel<<<dim3(12, 512), dim3(256), 0, stream>>>(x, qkv_w, qkv_b, Q, K, V);
    attn_kernel<<<dim3(4096), dim3(256), 0, stream>>>(Q, K, V, BF, Y);
    proj_kernel<<<dim3(4, 512), dim3(256), 0, stream>>>(Y, proj_w, proj_b, out);
}

// Round 3
// 269.423 us; speedup vs baseline: 2.6954x; 1.6903x over previous
//
#include <hip/hip_runtime.h>

typedef __attribute__((ext_vector_type(8))) short short8;
typedef __attribute__((ext_vector_type(4))) float floatx4;

#define CCH   256
#define QSCALE 0.17677669529663687f  // 32^-0.5

__device__ __forceinline__ unsigned short f2bf(float f) {
    unsigned u = __float_as_uint(f);
    u = u + 0x7fffu + ((u >> 16) & 1u);
    return (unsigned short)(u >> 16);
}
__device__ __forceinline__ float bf2f(unsigned short h) {
    return __uint_as_float(((unsigned)h) << 16);
}

__device__ __forceinline__ void gl_lds16(const void* g, void* l) {
    __builtin_amdgcn_global_load_lds((const __attribute__((address_space(1))) void*)g,
                                     (__attribute__((address_space(3))) void*)l, 16, 0, 0);
}

// token (w*512+n) -> flat spatial offset (*CCH) in x/out with +4 cyclic shift
__device__ __forceinline__ int spatial_off(int token) {
    int w = token >> 9, n = token & 511;
    int wh = w >> 4, ww = (w >> 2) & 3, wd = w & 3;
    int h1 = n >> 6, w1 = (n >> 3) & 7, d1 = n & 7;
    int gh = (wh * 8 + h1 + 4) & 31;
    int gw = (ww * 8 + w1 + 4) & 31;
    int gd = (wd * 8 + d1 + 4) & 31;
    return ((gh * 32 + gw) * 32 + gd) * CCH;
}

// ---------------- x (fp32, spatial) -> Xw (bf16, window-token order) ----------------
__global__ __launch_bounds__(256) void xconv(const float* __restrict__ x,
                                             ushort* __restrict__ Xw) {
    int tid = blockIdx.x * 256 + threadIdx.x;   // 1048576
    int token = tid >> 5, c8 = (tid & 31) * 8;
    const float* src = x + spatial_off(token) + c8;
    float4 a = *(const float4*)src;
    float4 b = *(const float4*)(src + 4);
    ushort o[8] = {f2bf(a.x), f2bf(a.y), f2bf(a.z), f2bf(a.w),
                   f2bf(b.x), f2bf(b.y), f2bf(b.z), f2bf(b.w)};
    *(short8*)(Xw + (size_t)token * 256 + c8) = *(short8*)o;
}

// ---------------- weights fp32 -> bf16 (QSCALE folded into first 256 rows of Wq) ----
__global__ __launch_bounds__(256) void wconv(const float* __restrict__ Wq,
                                             const float* __restrict__ Wp,
                                             ushort* __restrict__ Wqb,
                                             ushort* __restrict__ Wpb) {
    int tid = blockIdx.x * 256 + threadIdx.x;   // 262144
    if (tid < 196608) {
        float s = (tid < 65536) ? QSCALE : 1.0f;
        Wqb[tid] = f2bf(Wq[tid] * s);
    } else {
        int i = tid - 196608;
        Wpb[i] = f2bf(Wp[i]);
    }
}

// ---------------- rel-pos bias, pre-permuted into MFMA C-fragment order ----------------
__global__ __launch_bounds__(256) void bias_prep(const float* __restrict__ rpb,
                                                 ushort* __restrict__ BF) {
    int tid = blockIdx.x * 256 + threadIdx.x;   // 524288 total
    int lane = tid & 63, kt = (tid >> 6) & 31, qt = (tid >> 11) & 31, head = tid >> 16;
    int quad = lane >> 4, colc = lane & 15;
    int key = kt * 16 + colc;
    int h1k = key >> 6, w1k = (key >> 3) & 7, d1k = key & 7;
    ushort4 out;
#pragma unroll
    for (int r = 0; r < 4; ++r) {
        int qrow = qt * 16 + quad * 4 + r;
        int dh = (qrow >> 6) - h1k + 7;
        int dw = ((qrow >> 3) & 7) - w1k + 7;
        int dd = (qrow & 7) - d1k + 7;
        int idx = (dh * 15 + dw) * 15 + dd;
        ((ushort*)&out)[r] = f2bf(rpb[idx * 8 + head]);
    }
    *(ushort4*)(BF + (size_t)tid * 4) = out;
}

// ---------------- MFMA GEMM: C[32768 x 768] = Xw @ Wqb^T -> Q/K/V ----------------
// m97 structure: 128x128 tile, BK=64, global_load_lds 16B, xor-granule swizzle
__global__ __launch_bounds__(256) void gemm_qkv(
    const ushort* __restrict__ A,   // [32768][256] bf16
    const ushort* __restrict__ Bw,  // [768][256] bf16
    const float* __restrict__ bq,
    ushort* __restrict__ Q, ushort* __restrict__ K, ushort* __restrict__ V) {
    __shared__ short As[128 * 64];
    __shared__ short Bs[128 * 64];
    const int t = threadIdx.x;
    const int wv = t >> 6, lane = t & 63, quad = lane >> 4, col = lane & 15;
    const int m0 = blockIdx.y * 128, n0 = blockIdx.x * 128;
    const int wm = (wv & 1) * 64, wn = (wv >> 1) * 64;

    floatx4 zf = {0.f, 0.f, 0.f, 0.f};
    floatx4 acc[4][4];
#pragma unroll
    for (int i = 0; i < 4; ++i)
#pragma unroll
        for (int j = 0; j < 4; ++j) acc[i][j] = zf;

    for (int kk = 0; kk < 256; kk += 64) {
        __syncthreads();
#pragma unroll
        for (int i = 0; i < 4; ++i) {
            int s = i * 256 + t;
            int row = s >> 3, qs = s & 7;
            int qg = qs ^ (row & 7);
            gl_lds16(A + (size_t)(m0 + row) * 256 + kk + qg * 8,
                     As + (i * 256 + wv * 64) * 8);
        }
#pragma unroll
        for (int i = 0; i < 4; ++i) {
            int s = i * 256 + t;
            int row = s >> 3, qs = s & 7;
            int qg = qs ^ (row & 7);
            gl_lds16(Bw + (size_t)(n0 + row) * 256 + kk + qg * 8,
                     Bs + (i * 256 + wv * 64) * 8);
        }
        __syncthreads();
#pragma unroll
        for (int h = 0; h < 2; ++h) {
            short8 af[4], bf[4];
#pragma unroll
            for (int mi = 0; mi < 4; ++mi) {
                int row = wm + mi * 16 + col;
                af[mi] = *(const short8*)(As + (row * 8 + ((h * 4 + quad) ^ (row & 7))) * 8);
            }
#pragma unroll
            for (int ni = 0; ni < 4; ++ni) {
                int row = wn + ni * 16 + col;
                bf[ni] = *(const short8*)(Bs + (row * 8 + ((h * 4 + quad) ^ (row & 7))) * 8);
            }
#pragma unroll
            for (int mi = 0; mi < 4; ++mi)
#pragma unroll
                for (int ni = 0; ni < 4; ++ni)
                    acc[mi][ni] = __builtin_amdgcn_mfma_f32_16x16x32_bf16(af[mi], bf[ni], acc[mi][ni], 0, 0, 0);
        }
    }

#pragma unroll
    for (int ni = 0; ni < 4; ++ni) {
        int j = n0 + wn + ni * 16 + col;
        int three = j >> 8, head = (j >> 5) & 7, hd = j & 31;
        ushort* dst = (three == 0) ? Q : ((three == 1) ? K : V);
        float bias = bq[j] * ((j < 256) ? QSCALE : 1.0f);
#pragma unroll
        for (int mi = 0; mi < 4; ++mi) {
#pragma unroll
            for (int r = 0; r < 4; ++r) {
                int m = m0 + wm + mi * 16 + quad * 4 + r;
                int w = m >> 9, n = m & 511;
                dst[((size_t)(w * 8 + head) * 512 + n) * 32 + hd] = f2bf(acc[mi][ni][r] + bias);
            }
        }
    }
}

// ---------------- MFMA GEMM: out = Y @ Wpb^T + bp, scatter w/ reverse shift ----------
__global__ __launch_bounds__(256) void gemm_proj(
    const ushort* __restrict__ A,   // Y [32768][256] bf16
    const ushort* __restrict__ Bw,  // [256][256] bf16
    const float* __restrict__ bp,
    float* __restrict__ out) {
    __shared__ short As[128 * 64];
    __shared__ short Bs[128 * 64];
    const int t = threadIdx.x;
    const int wv = t >> 6, lane = t & 63, quad = lane >> 4, col = lane & 15;
    const int m0 = blockIdx.y * 128, n0 = blockIdx.x * 128;
    const int wm = (wv & 1) * 64, wn = (wv >> 1) * 64;

    floatx4 zf = {0.f, 0.f, 0.f, 0.f};
    floatx4 acc[4][4];
#pragma unroll
    for (int i = 0; i < 4; ++i)
#pragma unroll
        for (int j = 0; j < 4; ++j) acc[i][j] = zf;

    for (int kk = 0; kk < 256; kk += 64) {
        __syncthreads();
#pragma unroll
        for (int i = 0; i < 4; ++i) {
            int s = i * 256 + t;
            int row = s >> 3, qs = s & 7;
            int qg = qs ^ (row & 7);
            gl_lds16(A + (size_t)(m0 + row) * 256 + kk + qg * 8,
                     As + (i * 256 + wv * 64) * 8);
        }
#pragma unroll
        for (int i = 0; i < 4; ++i) {
            int s = i * 256 + t;
            int row = s >> 3, qs = s & 7;
            int qg = qs ^ (row & 7);
            gl_lds16(Bw + (size_t)(n0 + row) * 256 + kk + qg * 8,
                     Bs + (i * 256 + wv * 64) * 8);
        }
        __syncthreads();
#pragma unroll
        for (int h = 0; h < 2; ++h) {
            short8 af[4], bf[4];
#pragma unroll
            for (int mi = 0; mi < 4; ++mi) {
                int row = wm + mi * 16 + col;
                af[mi] = *(const short8*)(As + (row * 8 + ((h * 4 + quad) ^ (row & 7))) * 8);
            }
#pragma unroll
            for (int ni = 0; ni < 4; ++ni) {
                int row = wn + ni * 16 + col;
                bf[ni] = *(const short8*)(Bs + (row * 8 + ((h * 4 + quad) ^ (row & 7))) * 8);
            }
#pragma unroll
            for (int mi = 0; mi < 4; ++mi)
#pragma unroll
                for (int ni = 0; ni < 4; ++ni)
                    acc[mi][ni] = __builtin_amdgcn_mfma_f32_16x16x32_bf16(af[mi], bf[ni], acc[mi][ni], 0, 0, 0);
        }
    }

#pragma unroll
    for (int ni = 0; ni < 4; ++ni) {
        int j = n0 + wn + ni * 16 + col;
        float bias = bp[j];
#pragma unroll
        for (int mi = 0; mi < 4; ++mi) {
#pragma unroll
            for (int r = 0; r < 4; ++r) {
                int m = m0 + wm + mi * 16 + quad * 4 + r;
                out[spatial_off(m) + j] = acc[mi][ni][r] + bias;
            }
        }
    }
}

// ---------------- MFMA windowed attention ----------------
__global__ __launch_bounds__(256, 2) void attn_kernel(
    const ushort* __restrict__ Q, const ushort* __restrict__ K,
    const ushort* __restrict__ V, const ushort* __restrict__ BF,
    ushort* __restrict__ Y) {
    __shared__ short Kl[512 * 32];       // row-major [key][hd] bf16
    __shared__ short Vs[512 * 32];       // B-fragment order [kt*2+nt][lane][j]
    __shared__ short Ps[4][16 * 40];     // per-wave P transpose buffer (stride 40)

    const int t = threadIdx.x;
    const int bid = blockIdx.x;
    const int w = bid >> 6, head = (bid >> 3) & 7, qs = bid & 7;
    const int wh = w >> 4, ww = (w >> 2) & 3, wd = w & 3;
    const int wv = t >> 6, lane = t & 63, quad = lane >> 4, col = lane & 15;
    const int qt = qs * 4 + wv;

    const ushort* Kg = K + (size_t)(w * 8 + head) * 512 * 32;
    const ushort* Vg = V + (size_t)(w * 8 + head) * 512 * 32;

#pragma unroll
    for (int i = 0; i < 8; ++i) {
        int e = (i * 256 + t) * 8;
        *(short8*)(Kl + e) = *(const short8*)(Kg + e);
        short8 v = *(const short8*)(Vg + e);
        int r = e >> 5, c0 = e & 31;
        int base = (((r >> 5) * 2 + (c0 >> 4)) * 64 + ((r >> 3) & 3) * 16 + (c0 & 15)) * 8 + (r & 7);
#pragma unroll
        for (int m = 0; m < 8; ++m) Vs[base + m * 8] = v[m];
    }

    short8 qf = *(const short8*)(Q + ((size_t)(w * 8 + head) * 512 + qt * 16 + col) * 32 + quad * 8);
    __syncthreads();

    floatx4 zf = {0.f, 0.f, 0.f, 0.f};
    floatx4 acc[32];
#pragma unroll
    for (int tt = 0; tt < 32; ++tt) {
        short8 kf = *(const short8*)(Kl + tt * 512 + col * 32 + quad * 8);
        acc[tt] = __builtin_amdgcn_mfma_f32_16x16x32_bf16(qf, kf, zf, 0, 0, 0);
    }

    const ushort* bfp = BF + ((size_t)(head * 32 + qt) * 32 * 64 + lane) * 4;
    const bool boundary = (wh == 3) | (ww == 3) | (wd == 3);
    int cq[4];
#pragma unroll
    for (int r = 0; r < 4; ++r) {
        int qrow = qt * 16 + quad * 4 + r;
        int ch = (wh == 3) ? (1 + ((qrow >> 8) & 1)) : 0;
        int cw = (ww == 3) ? (1 + ((qrow >> 5) & 1)) : 0;
        int cd = (wd == 3) ? (1 + ((qrow >> 2) & 1)) : 0;
        cq[r] = ch * 16 + cw * 4 + cd;
    }
#pragma unroll
    for (int tt = 0; tt < 32; ++tt) {
        ushort4 bv = *(const ushort4*)(bfp + tt * 256);
        acc[tt][0] += bf2f(bv.x);
        acc[tt][1] += bf2f(bv.y);
        acc[tt][2] += bf2f(bv.z);
        acc[tt][3] += bf2f(bv.w);
        if (boundary) {
            int key = tt * 16 + col;
            int ch = (wh == 3) ? (1 + ((key >> 8) & 1)) : 0;
            int cw = (ww == 3) ? (1 + ((key >> 5) & 1)) : 0;
            int cd = (wd == 3) ? (1 + ((key >> 2) & 1)) : 0;
            int ck = ch * 16 + cw * 4 + cd;
#pragma unroll
            for (int r = 0; r < 4; ++r)
                acc[tt][r] += (cq[r] == ck) ? 0.f : -100.f;
        }
    }

    float rm[4], rs[4];
#pragma unroll
    for (int r = 0; r < 4; ++r) {
        float m = acc[0][r];
#pragma unroll
        for (int tt = 1; tt < 32; ++tt) m = fmaxf(m, acc[tt][r]);
        m = fmaxf(m, __shfl_xor(m, 1));
        m = fmaxf(m, __shfl_xor(m, 2));
        m = fmaxf(m, __shfl_xor(m, 4));
        m = fmaxf(m, __shfl_xor(m, 8));
        rm[r] = m * 1.442695041f;
        rs[r] = 0.f;
    }
#pragma unroll
    for (int tt = 0; tt < 32; ++tt) {
#pragma unroll
        for (int r = 0; r < 4; ++r) {
            float e = exp2f(fmaf(acc[tt][r], 1.442695041f, -rm[r]));
            acc[tt][r] = e;
            rs[r] += e;
        }
    }
#pragma unroll
    for (int r = 0; r < 4; ++r) {
        rs[r] += __shfl_xor(rs[r], 1);
        rs[r] += __shfl_xor(rs[r], 2);
        rs[r] += __shfl_xor(rs[r], 4);
        rs[r] += __shfl_xor(rs[r], 8);
    }

    short* PsW = &Ps[wv][0];
    floatx4 o0 = zf, o1 = zf;
#pragma unroll
    for (int kt = 0; kt < 16; ++kt) {
#pragma unroll
        for (int ttt = 0; ttt < 2; ++ttt) {
            floatx4 p = acc[kt * 2 + ttt];
#pragma unroll
            for (int r = 0; r < 4; ++r)
                PsW[(quad * 4 + r) * 40 + ttt * 16 + col] = (short)f2bf(p[r]);
        }
        asm volatile("s_waitcnt lgkmcnt(0)" ::: "memory");
        short8 pa = *(const short8*)(PsW + col * 40 + quad * 8);
        short8 v0 = *(const short8*)(Vs + (kt * 2 + 0) * 512 + lane * 8);
        short8 v1 = *(const short8*)(Vs + (kt * 2 + 1) * 512 + lane * 8);
        o0 = __builtin_amdgcn_mfma_f32_16x16x32_bf16(pa, v0, o0, 0, 0, 0);
        o1 = __builtin_amdgcn_mfma_f32_16x16x32_bf16(pa, v1, o1, 0, 0, 0);
        asm volatile("" ::: "memory");
    }

    ushort* Yb = Y + ((size_t)(w * 512) + qt * 16) * 256 + head * 32;
#pragma unroll
    for (int r = 0; r < 4; ++r) {
        float inv = 1.0f / rs[r];
        int row = quad * 4 + r;
        Yb[row * 256 + col] = f2bf(o0[r] * inv);
        Yb[row * 256 + 16 + col] = f2bf(o1[r] * inv);
    }
}

extern "C" void kernel_launch(void* const* d_in, const int* in_sizes, int n_in,
                              void* d_out, int out_size, void* d_ws, size_t ws_size,
                              hipStream_t stream) {
    const float* x      = (const float*)d_in[0];
    const float* qkv_w  = (const float*)d_in[1];
    const float* qkv_b  = (const float*)d_in[2];
    const float* proj_w = (const float*)d_in[3];
    const float* proj_b = (const float*)d_in[4];
    const float* rpb    = (const float*)d_in[5];
    float* out = (float*)d_out;

    // ws layout (ushorts): Xw 8.39M | Q 8.39M | K 8.39M | V 8.39M | Y 8.39M | BF 2.1M | Wqb 196608 | Wpb 65536
    ushort* Xw  = (ushort*)d_ws;
    ushort* Q   = Xw + 8388608;
    ushort* K   = Q + 8388608;
    ushort* V   = K + 8388608;
    ushort* Y   = V + 8388608;
    ushort* BF  = Y + 8388608;
    ushort* Wqb = BF + 2097152;
    ushort* Wpb = Wqb + 196608;

    xconv<<<dim3(4096), dim3(256), 0, stream>>>(x, Xw);
    wconv<<<dim3(1024), dim3(256), 0, stream>>>(qkv_w, proj_w, Wqb, Wpb);
    bias_prep<<<dim3(2048), dim3(256), 0, stream>>>(rpb, BF);
    gemm_qkv<<<dim3(6, 256), dim3(256), 0, stream>>>(Xw, Wqb, qkv_b, Q, K, V);
    attn_kernel<<<dim3(4096), dim3(256), 0, stream>>>(Q, K, V, BF, Y);
    gemm_proj<<<dim3(2, 256), dim3(256), 0, stream>>>(Y, Wpb, proj_b, out);
}